// Round 1
// baseline (54640.796 us; speedup 1.0000x reference)
//
#include <hip/hip_runtime.h>
#include <math.h>

#define BB 32
#define TT 512
#define DD 512
#define UU 512
#define G3 1536   // 3*U

__device__ __forceinline__ float hsig(float x) {
    return fminf(fmaxf(fmaf(0.2f, x, 0.5f), 0.0f), 1.0f);
}

// Per-step kernel 1: compute z, r, rh = r*h for all columns, both directions.
// Fuses the input projection x_t @ W[:, zcols|rcols] into the dot products.
// grid: 128 blocks = 2 dirs * 64 column-blocks of 8 cols; block: 256 thr =
// 8 cols * 32 batches.
__global__ __launch_bounds__(256) void gru_gates(
    const float* __restrict__ x,
    const float* __restrict__ Wf, const float* __restrict__ Uf, const float* __restrict__ bf,
    const float* __restrict__ Wb, const float* __restrict__ Ub, const float* __restrict__ bb,
    float* __restrict__ hbuf, float* __restrict__ zbuf, float* __restrict__ rhbuf,
    int t)
{
    const int blk  = blockIdx.x;
    const int dir  = blk >> 6;         // 0 fwd, 1 bwd
    const int jblk = blk & 63;         // 64 col-blocks of 8
    const int j    = jblk * 8 + (threadIdx.x & 7);
    const int b    = threadIdx.x >> 3; // 0..31

    const float* Wm   = dir ? Wb : Wf;
    const float* Um   = dir ? Ub : Uf;
    const float* bias = dir ? bb : bf;
    const int trow    = dir ? (TT - 1 - t) : t;

    const float* xrow = x + ((size_t)b * TT + trow) * DD;
    const float* hrow = hbuf + ((size_t)dir * BB + b) * UU;

    const float4* x4 = (const float4*)xrow;
    const float4* h4 = (const float4*)hrow;

    float accz = 0.f, accr = 0.f;
    #pragma unroll 4
    for (int k4 = 0; k4 < DD / 4; ++k4) {
        float4 xv = x4[k4];
        float4 hv = h4[k4];
        int k = k4 * 4;
        const float* wz = Wm + (size_t)k * G3 + j;
        const float* wr = wz + UU;
        const float* uz = Um + (size_t)k * G3 + j;
        const float* ur = uz + UU;
        accz = fmaf(xv.x, wz[0],        accz);
        accz = fmaf(xv.y, wz[G3],       accz);
        accz = fmaf(xv.z, wz[2 * G3],   accz);
        accz = fmaf(xv.w, wz[3 * G3],   accz);
        accr = fmaf(xv.x, wr[0],        accr);
        accr = fmaf(xv.y, wr[G3],       accr);
        accr = fmaf(xv.z, wr[2 * G3],   accr);
        accr = fmaf(xv.w, wr[3 * G3],   accr);
        accz = fmaf(hv.x, uz[0],        accz);
        accz = fmaf(hv.y, uz[G3],       accz);
        accz = fmaf(hv.z, uz[2 * G3],   accz);
        accz = fmaf(hv.w, uz[3 * G3],   accz);
        accr = fmaf(hv.x, ur[0],        accr);
        accr = fmaf(hv.y, ur[G3],       accr);
        accr = fmaf(hv.z, ur[2 * G3],   accr);
        accr = fmaf(hv.w, ur[3 * G3],   accr);
    }
    accz += bias[j];
    accr += bias[UU + j];

    const float z = hsig(accz);
    const float r = hsig(accr);
    const size_t idx = ((size_t)dir * BB + b) * UU + j;
    zbuf[idx]  = z;
    rhbuf[idx] = r * hrow[j];
}

// Per-step kernel 2: cand = tanh(xh + rh @ Uh), h_new = z*h + (1-z)*cand,
// write h and output. grid: 128 blocks = 2 dirs * 64 col-blocks of 8.
__global__ __launch_bounds__(256) void gru_cand(
    const float* __restrict__ x,
    const float* __restrict__ Wf, const float* __restrict__ Uf, const float* __restrict__ bf,
    const float* __restrict__ Wb, const float* __restrict__ Ub, const float* __restrict__ bb,
    float* __restrict__ hbuf, const float* __restrict__ zbuf, const float* __restrict__ rhbuf,
    float* __restrict__ out, int t)
{
    const int blk  = blockIdx.x;
    const int dir  = blk >> 6;
    const int jblk = blk & 63;
    const int j    = jblk * 8 + (threadIdx.x & 7);
    const int b    = threadIdx.x >> 3;

    const float* Wm   = dir ? Wb : Wf;
    const float* Um   = dir ? Ub : Uf;
    const float* bias = dir ? bb : bf;
    const int trow    = dir ? (TT - 1 - t) : t;

    const float* xrow  = x + ((size_t)b * TT + trow) * DD;
    const float* rhrow = rhbuf + ((size_t)dir * BB + b) * UU;

    const float4* x4  = (const float4*)xrow;
    const float4* rh4 = (const float4*)rhrow;

    float acc = 0.f;
    #pragma unroll 4
    for (int k4 = 0; k4 < DD / 4; ++k4) {
        float4 xv = x4[k4];
        float4 rv = rh4[k4];
        int k = k4 * 4;
        const float* wh = Wm + (size_t)k * G3 + 2 * UU + j;
        const float* uh = Um + (size_t)k * G3 + 2 * UU + j;
        acc = fmaf(xv.x, wh[0],      acc);
        acc = fmaf(xv.y, wh[G3],     acc);
        acc = fmaf(xv.z, wh[2 * G3], acc);
        acc = fmaf(xv.w, wh[3 * G3], acc);
        acc = fmaf(rv.x, uh[0],      acc);
        acc = fmaf(rv.y, uh[G3],     acc);
        acc = fmaf(rv.z, uh[2 * G3], acc);
        acc = fmaf(rv.w, uh[3 * G3], acc);
    }
    acc += bias[2 * UU + j];

    const float cand = tanhf(acc);
    const size_t idx = ((size_t)dir * BB + b) * UU + j;
    const float z = zbuf[idx];
    const float h = hbuf[idx];
    const float hn = fmaf(z, h - cand, cand);  // z*h + (1-z)*cand

    hbuf[idx] = hn;
    // out[b][t][dir*U + j]; bwd outputs stay in scan order (reference does
    // not flip outs_b back).
    out[((size_t)b * TT + t) * (2 * UU) + (size_t)dir * UU + j] = hn;
}

extern "C" void kernel_launch(void* const* d_in, const int* in_sizes, int n_in,
                              void* d_out, int out_size, void* d_ws, size_t ws_size,
                              hipStream_t stream) {
    const float* x  = (const float*)d_in[0];
    const float* Wf = (const float*)d_in[1];
    const float* Uf = (const float*)d_in[2];
    const float* bf = (const float*)d_in[3];
    const float* Wb = (const float*)d_in[4];
    const float* Ub = (const float*)d_in[5];
    const float* bb = (const float*)d_in[6];
    float* out = (float*)d_out;

    // ws layout: h[2][B][U], z[2][B][U], rh[2][B][U] (fp32)
    float* hbuf  = (float*)d_ws;
    float* zbuf  = hbuf + 2 * BB * UU;
    float* rhbuf = zbuf + 2 * BB * UU;

    // h0 = 0 for both directions (ws is poisoned before every launch)
    hipMemsetAsync(hbuf, 0, (size_t)2 * BB * UU * sizeof(float), stream);

    for (int t = 0; t < TT; ++t) {
        gru_gates<<<dim3(128), dim3(256), 0, stream>>>(
            x, Wf, Uf, bf, Wb, Ub, bb, hbuf, zbuf, rhbuf, t);
        gru_cand<<<dim3(128), dim3(256), 0, stream>>>(
            x, Wf, Uf, bf, Wb, Ub, bb, hbuf, zbuf, rhbuf, out, t);
    }
}

// Round 2
// 7397.512 us; speedup vs baseline: 7.3864x; 7.3864x over previous
//
#include <hip/hip_runtime.h>
#include <math.h>

#define BB 32
#define TT 512
#define DD 512
#define UU 512
#define G3 1536   // 3*U
#define CHUNK 64  // time steps per xg chunk

__device__ __forceinline__ float hsig(float x) {
    return fminf(fmaxf(fmaf(0.2f, x, 0.5f), 0.0f), 1.0f);
}

// ---------------------------------------------------------------------------
// Kernel A: x_gates chunk GEMM.
// xgc[dir][i][b][n] = sum_k x[b][t_phys][k] * W_dir[k][n] + bias_dir[n]
// where t_phys = t0+i (fwd) or T-1-t0-i (bwd).  M=2048 rows (i*32+b) per dir,
// N=1536, K=512.  128x64 tile, 256 threads, 8x4 microtile, BK=16.
// ---------------------------------------------------------------------------
__global__ __launch_bounds__(256) void xg_gemm(
    const float* __restrict__ x,
    const float* __restrict__ Wf, const float* __restrict__ bf,
    const float* __restrict__ Wb, const float* __restrict__ bb,
    float* __restrict__ xgc, int t0)
{
    const int dir = blockIdx.z;
    const int n0  = blockIdx.x * 64;
    const int m0  = blockIdx.y * 128;
    const float* W    = dir ? Wb : Wf;
    const float* bias = dir ? bb : bf;

    __shared__ float As[16][132];  // [k][m] transposed, pad row to 132
    __shared__ float Bs[16][64];   // [k][n]

    const int tid = threadIdx.x;
    const int tx = tid & 15, ty = tid >> 4;

    float acc[8][4];
    #pragma unroll
    for (int i = 0; i < 8; ++i)
        #pragma unroll
        for (int q = 0; q < 4; ++q) acc[i][q] = 0.f;

    // A load rows: each thread loads rows lmr and lmr+64, 1 float4 of k each
    const int lmr = tid >> 2;
    const int ak4 = (tid & 3) * 4;
    const float* arow0;
    const float* arow1;
    {
        int m = m0 + lmr;
        int b = m & 31, i = m >> 5;
        int tp = dir ? (TT - 1 - t0 - i) : (t0 + i);
        arow0 = x + ((size_t)b * TT + tp) * DD;
        m = m0 + lmr + 64;
        b = m & 31; i = m >> 5;
        tp = dir ? (TT - 1 - t0 - i) : (t0 + i);
        arow1 = x + ((size_t)b * TT + tp) * DD;
    }
    const float* bsrc = W + (size_t)(tid >> 4) * G3 + n0 + (tid & 15) * 4;

    for (int k0 = 0; k0 < DD; k0 += 16) {
        float4 a0 = *(const float4*)(arow0 + k0 + ak4);
        float4 a1 = *(const float4*)(arow1 + k0 + ak4);
        float4 bv = *(const float4*)(bsrc + (size_t)k0 * G3);
        __syncthreads();
        As[ak4 + 0][lmr] = a0.x;  As[ak4 + 1][lmr] = a0.y;
        As[ak4 + 2][lmr] = a0.z;  As[ak4 + 3][lmr] = a0.w;
        As[ak4 + 0][lmr + 64] = a1.x;  As[ak4 + 1][lmr + 64] = a1.y;
        As[ak4 + 2][lmr + 64] = a1.z;  As[ak4 + 3][lmr + 64] = a1.w;
        *(float4*)&Bs[tid >> 4][(tid & 15) * 4] = bv;
        __syncthreads();
        #pragma unroll
        for (int kk = 0; kk < 16; ++kk) {
            float4 b4 = *(const float4*)&Bs[kk][tx * 4];
            #pragma unroll
            for (int i = 0; i < 8; ++i) {
                float a = As[kk][ty * 8 + i];
                acc[i][0] = fmaf(a, b4.x, acc[i][0]);
                acc[i][1] = fmaf(a, b4.y, acc[i][1]);
                acc[i][2] = fmaf(a, b4.z, acc[i][2]);
                acc[i][3] = fmaf(a, b4.w, acc[i][3]);
            }
        }
    }

    float4 bv = *(const float4*)(bias + n0 + tx * 4);
    #pragma unroll
    for (int i = 0; i < 8; ++i) {
        int m = m0 + ty * 8 + i;
        float4 o;
        o.x = acc[i][0] + bv.x;  o.y = acc[i][1] + bv.y;
        o.z = acc[i][2] + bv.z;  o.w = acc[i][3] + bv.w;
        *(float4*)(xgc + ((size_t)dir * (CHUNK * BB) + m) * G3 + n0 + tx * 4) = o;
    }
}

// ---------------------------------------------------------------------------
// Phase 1 (per step): z = hsig(xz + h@Uz), r = hsig(xr + h@Ur), rh = r*h.
// grid (32 jblk, 4 bblk, 2 dir) x 512 thr.  Thread = (j16, gate, b8, khalf):
// K=256 dot each, LDS reduce.  h rows staged in LDS.
// ---------------------------------------------------------------------------
__global__ __launch_bounds__(512) void gru_phase1(
    const float* __restrict__ Uf, const float* __restrict__ Ub,
    const float* __restrict__ xgc,
    const float* __restrict__ hbuf, float* __restrict__ zbuf,
    float* __restrict__ rhbuf, int i)
{
    const int jblk = blockIdx.x;
    const int bblk = blockIdx.y;
    const int dir  = blockIdx.z;
    const float* U = dir ? Ub : Uf;

    __shared__ float h_lds[8][512];
    __shared__ float red[256];

    const int tid = threadIdx.x;
    const int j16 = tid & 15;
    const int g   = (tid >> 4) & 1;
    const int b8  = (tid >> 5) & 7;
    const int kh  = tid >> 8;
    const int b0  = bblk * 8;

    {
        const float4* src = (const float4*)(hbuf + ((size_t)dir * BB + b0) * UU);
        float4* dst = (float4*)&h_lds[0][0];
        dst[tid]       = src[tid];
        dst[tid + 512] = src[tid + 512];
    }
    __syncthreads();

    const int jg  = jblk * 16 + j16;
    const int col = g * 512 + jg;
    const float* Ucol = U + col;

    float acc = 0.f;
    const int kbeg = kh * 256;
    #pragma unroll 16
    for (int k = 0; k < 256; ++k)
        acc = fmaf(h_lds[b8][kbeg + k], Ucol[(size_t)(kbeg + k) * G3], acc);

    if (kh) red[tid - 256] = acc;
    __syncthreads();
    if (!kh) {
        acc += red[tid];
        const int b = b0 + b8;
        float val = xgc[(((size_t)dir * CHUNK + i) * BB + b) * G3 + col] + acc;
        float v = hsig(val);
        size_t idx = ((size_t)dir * BB + b) * UU + jg;
        if (g == 0) zbuf[idx] = v;
        else        rhbuf[idx] = v * h_lds[b8][jg];
    }
}

// ---------------------------------------------------------------------------
// Phase 2 (per step): cand = tanh(xh + rh@Uh); h = z*h + (1-z)*cand; write out.
// grid (32 jblk, 4 bblk, 2 dir) x 512 thr.  Thread = (j16, b8, kquarter):
// K=128 dot each, LDS reduce.  rh rows staged in LDS.
// ---------------------------------------------------------------------------
__global__ __launch_bounds__(512) void gru_phase2(
    const float* __restrict__ Uf, const float* __restrict__ Ub,
    const float* __restrict__ xgc,
    float* __restrict__ hbuf, const float* __restrict__ zbuf,
    const float* __restrict__ rhbuf, float* __restrict__ out, int i, int t)
{
    const int jblk = blockIdx.x;
    const int bblk = blockIdx.y;
    const int dir  = blockIdx.z;
    const float* U = dir ? Ub : Uf;

    __shared__ float rh_lds[8][512];
    __shared__ float red[384];

    const int tid = threadIdx.x;
    const int lo  = tid & 127;
    const int j16 = tid & 15;
    const int b8  = (tid >> 4) & 7;
    const int kq  = tid >> 7;
    const int b0  = bblk * 8;

    {
        const float4* src = (const float4*)(rhbuf + ((size_t)dir * BB + b0) * UU);
        float4* dst = (float4*)&rh_lds[0][0];
        dst[tid]       = src[tid];
        dst[tid + 512] = src[tid + 512];
    }
    __syncthreads();

    const int jg = jblk * 16 + j16;
    const float* Ucol = U + 1024 + jg;

    float acc = 0.f;
    const int kbeg = kq * 128;
    #pragma unroll 16
    for (int k = 0; k < 128; ++k)
        acc = fmaf(rh_lds[b8][kbeg + k], Ucol[(size_t)(kbeg + k) * G3], acc);

    if (kq) red[(kq - 1) * 128 + lo] = acc;
    __syncthreads();
    if (kq == 0) {
        acc += red[lo] + red[128 + lo] + red[256 + lo];
        const int b = b0 + b8;
        float val = xgc[(((size_t)dir * CHUNK + i) * BB + b) * G3 + 1024 + jg] + acc;
        float cand = tanhf(val);
        size_t idx = ((size_t)dir * BB + b) * UU + jg;
        float z = zbuf[idx], h = hbuf[idx];
        float hn = fmaf(z, h - cand, cand);   // z*h + (1-z)*cand
        hbuf[idx] = hn;
        out[((size_t)b * TT + t) * (2 * UU) + (size_t)dir * UU + jg] = hn;
    }
}

extern "C" void kernel_launch(void* const* d_in, const int* in_sizes, int n_in,
                              void* d_out, int out_size, void* d_ws, size_t ws_size,
                              hipStream_t stream) {
    const float* x  = (const float*)d_in[0];
    const float* Wf = (const float*)d_in[1];
    const float* Uf = (const float*)d_in[2];
    const float* bf = (const float*)d_in[3];
    const float* Wb = (const float*)d_in[4];
    const float* Ub = (const float*)d_in[5];
    const float* bb = (const float*)d_in[6];
    float* out = (float*)d_out;

    // ws: h[2][32][512], z, rh (384 KB) then xg chunk [2][64][32][1536] (~25 MB)
    float* hbuf  = (float*)d_ws;
    float* zbuf  = hbuf + 2 * BB * UU;
    float* rhbuf = zbuf + 2 * BB * UU;
    float* xgc   = rhbuf + 2 * BB * UU;

    hipMemsetAsync(hbuf, 0, (size_t)2 * BB * UU * sizeof(float), stream);

    for (int c = 0; c < TT / CHUNK; ++c) {
        const int t0 = c * CHUNK;
        xg_gemm<<<dim3(24, 16, 2), 256, 0, stream>>>(x, Wf, bf, Wb, bb, xgc, t0);
        for (int i = 0; i < CHUNK; ++i) {
            const int t = t0 + i;
            gru_phase1<<<dim3(32, 4, 2), 512, 0, stream>>>(
                Uf, Ub, xgc, hbuf, zbuf, rhbuf, i);
            gru_phase2<<<dim3(32, 4, 2), 512, 0, stream>>>(
                Uf, Ub, xgc, hbuf, zbuf, rhbuf, out, i, t);
        }
    }
}